// Round 8
// baseline (259.789 us; speedup 1.0000x reference)
//
#include <hip/hip_runtime.h>
#include <hip/hip_bf16.h>

#define HEADS  16
#define DHEAD  64
#define BATCH  4
#define SEQ    2048
#define DIM    1024
#define KVROWS 2112   // 2049 (null + SEQ) padded up to multiple of 64
#define CSHIFT 24.0f  // static softmax shift (log2 domain); s' ~ N(0,1.44)

typedef __hip_bfloat16 bf16;
typedef __attribute__((ext_vector_type(8))) short s8v;   // 8 x bf16 (4 VGPRs)
typedef __attribute__((ext_vector_type(4))) short s4v;   // 4 x bf16
typedef __attribute__((ext_vector_type(4))) float f4v;   // MFMA accumulator

// async global->LDS, 16B per lane, dest = wave-uniform base + lane*16
__device__ __forceinline__ void gl_lds16(const void* g, void* l) {
  __builtin_amdgcn_global_load_lds(
      (const __attribute__((address_space(1))) unsigned int*)g,
      (__attribute__((address_space(3))) unsigned int*)l, 16, 0, 0);
}

// ---------------------------------------------------------------------------
// fp32 -> bf16 bulk convert (8 elements/thread)
// ---------------------------------------------------------------------------
__global__ void convert_kernel(const float* __restrict__ in, bf16* __restrict__ out) {
  const size_t i = ((size_t)blockIdx.x * 256 + threadIdx.x) * 8;
  const float4 a = *(const float4*)&in[i];
  const float4 b = *(const float4*)&in[i + 4];
  bf16 v[8] = {__float2bfloat16(a.x), __float2bfloat16(a.y),
               __float2bfloat16(a.z), __float2bfloat16(a.w),
               __float2bfloat16(b.x), __float2bfloat16(b.y),
               __float2bfloat16(b.z), __float2bfloat16(b.w)};
  *(s8v*)&out[i] = *(s8v*)v;
}

// ---------------------------------------------------------------------------
// Transpose+convert: fp32 [R][C] -> bf16 [C][R]; R,C multiples of 32
// ---------------------------------------------------------------------------
__global__ void transpose_kernel(const float* __restrict__ in, bf16* __restrict__ out,
                                 int R, int C) {
  __shared__ bf16 tile[32][33];
  const int c0 = blockIdx.x * 32, r0 = blockIdx.y * 32;
  const int tx = threadIdx.x, ty = threadIdx.y;
#pragma unroll
  for (int i = 0; i < 32; i += 8)
    tile[ty + i][tx] = __float2bfloat16(in[(size_t)(r0 + ty + i) * C + c0 + tx]);
  __syncthreads();
#pragma unroll
  for (int i = 0; i < 32; i += 8)
    out[(size_t)(c0 + ty + i) * R + r0 + tx] = tile[tx][ty + i];
}

// ---------------------------------------------------------------------------
// Async GEMM: C = alpha * A[M][K] @ BT[N][K]^T. 64x128 tile (small-shape
// regime fix: 1024 blocks = 4/CU so barrier drains overlap across blocks).
// BK=32, 4 waves (2x2): wave = 32x64 subtile, 2x4 MFMA 16x16x32 frags.
// Staging: global_load_lds w16 into UNPADDED tiles; bank swizzle embedded in
// the per-lane GLOBAL address (chunk' = chunk ^ ((row%16)>>1 & 3)).
// ---------------------------------------------------------------------------
template <typename OT>
__global__ __launch_bounds__(256) void gemm_async_kernel(
    const bf16* __restrict__ A, const bf16* __restrict__ BT,
    OT* __restrict__ C, int K, int c_ld, float alpha) {
  __shared__ bf16 As[64 * 32];    // 4 KB
  __shared__ bf16 Bs[128 * 32];   // 8 KB
  const int m0 = blockIdx.x * 64, n0 = blockIdx.y * 128;
  const int t = threadIdx.x;
  const int w = t >> 6, l = t & 63, lr = l & 15, lq = l >> 4;
  const int wm = (w & 1) * 32, wn = (w >> 1) * 64;
  f4v acc[2][4] = {};

  const int rowl = l >> 2;
  const int cl = ((l & 3) ^ ((l >> 3) & 3)) * 8;
  const bf16* gA  = A  + (size_t)(m0 + 16 * w + rowl) * K + cl;
  const bf16* gB0 = BT + (size_t)(n0 + 32 * w + rowl) * K + cl;
  const bf16* gB1 = BT + (size_t)(n0 + 32 * w + 16 + rowl) * K + cl;
  bf16* lA  = As + w * 512;             // 512 shorts = 16 rows x 32
  bf16* lB0 = Bs + (2 * w) * 512;
  bf16* lB1 = Bs + (2 * w + 1) * 512;

  const int sw = lq ^ ((lr >> 1) & 3);
  const s8v* As16 = (const s8v*)As;
  const s8v* Bs16 = (const s8v*)Bs;

  for (int k0 = 0; k0 < K; k0 += 32) {
    __syncthreads();
    gl_lds16(gA + k0, lA);
    gl_lds16(gB0 + k0, lB0);
    gl_lds16(gB1 + k0, lB1);
    __syncthreads();  // drains vmcnt -> LDS valid
    s8v a[2], b[4];
#pragma unroll
    for (int mt = 0; mt < 2; mt++) a[mt] = As16[(wm + mt * 16 + lr) * 4 + sw];
#pragma unroll
    for (int ct = 0; ct < 4; ct++) b[ct] = Bs16[(wn + ct * 16 + lr) * 4 + sw];
#pragma unroll
    for (int mt = 0; mt < 2; mt++)
#pragma unroll
      for (int ct = 0; ct < 4; ct++)
        acc[mt][ct] = __builtin_amdgcn_mfma_f32_16x16x32_bf16(a[mt], b[ct], acc[mt][ct], 0, 0, 0);
  }
#pragma unroll
  for (int mt = 0; mt < 2; mt++)
#pragma unroll
    for (int ct = 0; ct < 4; ct++)
#pragma unroll
      for (int r = 0; r < 4; r++) {
        const int row = m0 + wm + mt * 16 + lq * 4 + r;
        const int col = n0 + wn + ct * 16 + lr;
        const float v = acc[mt][ct][r] * alpha;
        if constexpr (__is_same(OT, float)) C[(size_t)row * c_ld + col] = v;
        else                                C[(size_t)row * c_ld + col] = __float2bfloat16(v);
      }
}

// ---------------------------------------------------------------------------
// KV GEMM: kv = x @ WkvT^T (N=64), dual-layout epilogue -> kvbuf + kvbufT.
// ---------------------------------------------------------------------------
__global__ __launch_bounds__(256) void gemm_kv_kernel(
    const bf16* __restrict__ A, const bf16* __restrict__ BT,
    bf16* __restrict__ kvbuf, bf16* __restrict__ kvbufT, int K) {
  __shared__ bf16 As[128][32];
  __shared__ bf16 Bs[64][32];
  const int m0 = blockIdx.x * 128;
  const int t = threadIdx.x;
  const int w = t >> 6, l = t & 63, lr = l & 15, lq = l >> 4;
  f4v acc[2][4] = {};
  const int arow = t >> 1, acol = (t & 1) * 16;
  const int brow = t >> 2, bcol = (t & 3) * 8;

  for (int k0 = 0; k0 < K; k0 += 32) {
    __syncthreads();
    *(s8v*)&As[arow][acol]     = *(const s8v*)&A[(size_t)(m0 + arow) * K + k0 + acol];
    *(s8v*)&As[arow][acol + 8] = *(const s8v*)&A[(size_t)(m0 + arow) * K + k0 + acol + 8];
    *(s8v*)&Bs[brow][bcol]     = *(const s8v*)&BT[(size_t)brow * K + k0 + bcol];
    __syncthreads();
    s8v a0 = *(const s8v*)&As[w * 32 + lr][lq * 8];
    s8v a1 = *(const s8v*)&As[w * 32 + 16 + lr][lq * 8];
#pragma unroll
    for (int ct = 0; ct < 4; ct++) {
      s8v bf = *(const s8v*)&Bs[ct * 16 + lr][lq * 8];
      acc[0][ct] = __builtin_amdgcn_mfma_f32_16x16x32_bf16(a0, bf, acc[0][ct], 0, 0, 0);
      acc[1][ct] = __builtin_amdgcn_mfma_f32_16x16x32_bf16(a1, bf, acc[1][ct], 0, 0, 0);
    }
  }
#pragma unroll
  for (int mt = 0; mt < 2; mt++)
#pragma unroll
    for (int ct = 0; ct < 4; ct++)
#pragma unroll
      for (int r = 0; r < 4; r++) {
        const int m = m0 + w * 32 + mt * 16 + lq * 4 + r;
        const int col = ct * 16 + lr;
        const int bb = m >> 11, jj = (m & 2047) + 1;
        const bf16 v = __float2bfloat16(acc[mt][ct][r]);
        kvbuf [(size_t)(bb * KVROWS + jj) * DHEAD + col] = v;
        kvbufT[(size_t)(bb * DHEAD + col) * KVROWS + jj] = v;
      }
}

// ---------------------------------------------------------------------------
// Fill row 0 (null_kv) and tail rows 2049..2111 (zeros) in BOTH kv layouts.
// ---------------------------------------------------------------------------
__global__ void fill_null_tail_kernel(const float* __restrict__ null_kv,
                                      bf16* __restrict__ kvbuf,
                                      bf16* __restrict__ kvbufT) {
  const int idx = blockIdx.x * 256 + threadIdx.x;
  const int d = idx & 63;
  const int s = (idx >> 6) & 63;
  const int b = idx >> 12;
  const int row = (s == 0) ? 0 : 2048 + s;
  const bf16 v = (s == 0) ? __float2bfloat16(null_kv[d]) : __float2bfloat16(0.f);
  kvbuf [(size_t)(b * KVROWS + row) * DHEAD + d] = v;
  kvbufT[(size_t)(b * DHEAD + d) * KVROWS + row] = v;
}

// ---------------------------------------------------------------------------
// Transposed flash attention, 2 HEADS PER BLOCK, static-shift softmax.
// S^T = KV.Q^T with acc pre-init -CSHIFT; P = exp2(S^T) directly (no running
// max / no rescale: shift-invariance + fp scale-invariance make it exact;
// s' ~ N(0,1.44), 8-sigma max << 24). l accumulated per-lane, reduced once.
// KV staging and barriers shared by both heads. O^T = KV^T.P^T. LDS rows
// padded to 68 shorts (bank floor for b128/b64 + staging). exp2-domain.
// ---------------------------------------------------------------------------
__global__ __launch_bounds__(256) void attn_kernel(
    const bf16* __restrict__ q,    // [B*SEQ][DIM] (pre-scaled by 0.125*log2e)
    const bf16* __restrict__ kv,   // [B][KVROWS][64]
    const bf16* __restrict__ kvT,  // [B][64][KVROWS]
    bf16* __restrict__ o) {        // [B*SEQ][DIM]
  __shared__ bf16 kvs [64][68];    // 8.5 KB
  __shared__ bf16 kvsT[64][68];    // 8.5 KB
  __shared__ bf16 Ps[4][16][68];   // 8.5 KB (wave-local, reused per head)
  const int t = threadIdx.x, w = t >> 6, l = t & 63, lr = l & 15, lq = l >> 4;
  const int blk = blockIdx.x;                 // 1024 = 32 qt x 8 hp x 4 b
  const int qt = 31 - (blk >> 5);             // longest q-tiles first
  const int rem = blk & 31, hp = rem >> 2, b = rem & 3;
  const int q0 = qt * 64;
  const int iw = q0 + w * 16 + lr;

  const bf16* qbase = q + ((size_t)(b * SEQ) + iw) * DIM + hp * 128;
  s8v qb[2][2];
#pragma unroll
  for (int hh = 0; hh < 2; hh++) {
    qb[hh][0] = *(const s8v*)&qbase[hh * 64 + lq * 8];
    qb[hh][1] = *(const s8v*)&qbase[hh * 64 + 32 + lq * 8];
  }

  f4v oaccT[2][4] = {};
  float l_lane[2] = {0.f, 0.f};
  const bf16* kvb  = kv  + (size_t)b * KVROWS * DHEAD;
  const bf16* kvTb = kvT + (size_t)b * DHEAD * KVROWS;
  const int jend = q0 + 65;
  const int srow = t >> 2, scol = (t & 3) * 16;

  for (int j0 = 0; j0 < jend; j0 += 64) {
    __syncthreads();
    *(s8v*)&kvs[srow][scol]      = *(const s8v*)&kvb[(size_t)(j0 + srow) * DHEAD + scol];
    *(s8v*)&kvs[srow][scol + 8]  = *(const s8v*)&kvb[(size_t)(j0 + srow) * DHEAD + scol + 8];
    *(s8v*)&kvsT[srow][scol]     = *(const s8v*)&kvTb[(size_t)srow * KVROWS + j0 + scol];
    *(s8v*)&kvsT[srow][scol + 8] = *(const s8v*)&kvTb[(size_t)srow * KVROWS + j0 + scol + 8];
    __syncthreads();

    // S^T for both heads (KV A-frags read once)
    f4v st[2][4];
#pragma unroll
    for (int jt = 0; jt < 4; jt++) {
      s8v a0 = *(const s8v*)&kvs[jt * 16 + lr][lq * 8];
      s8v a1 = *(const s8v*)&kvs[jt * 16 + lr][32 + lq * 8];
#pragma unroll
      for (int hh = 0; hh < 2; hh++) {
        f4v z = {-CSHIFT, -CSHIFT, -CSHIFT, -CSHIFT};
        z = __builtin_amdgcn_mfma_f32_16x16x32_bf16(a0, qb[hh][0], z, 0, 0, 0);
        z = __builtin_amdgcn_mfma_f32_16x16x32_bf16(a1, qb[hh][1], z, 0, 0, 0);
        st[hh][jt] = z;
      }
    }

    const bool diag = (j0 + 62 > q0 + w * 16);  // wave-uniform
#pragma unroll
    for (int hh = 0; hh < 2; hh++) {
      if (diag) {
#pragma unroll
        for (int jt = 0; jt < 4; jt++)
#pragma unroll
          for (int r = 0; r < 4; r++) {
            const int jg = j0 + jt * 16 + lq * 4 + r;
            if (jg > iw + 1) st[hh][jt][r] = -1e30f;
          }
      }
      float rs = 0.f;
#pragma unroll
      for (int jt = 0; jt < 4; jt++)
#pragma unroll
        for (int r = 0; r < 4; r++) {
          const float pv = exp2f(st[hh][jt][r]);
          st[hh][jt][r] = pv;
          rs += pv;
        }
      l_lane[hh] += rs;

      // P^T -> Ps[w] (wave-local), b64 writes
#pragma unroll
      for (int jt = 0; jt < 4; jt++) {
        s4v pk;
#pragma unroll
        for (int r = 0; r < 4; r++) {
          bf16 h16 = __float2bfloat16(st[hh][jt][r]);
          pk[r] = *(short*)&h16;
        }
        *(s4v*)&Ps[w][lr][jt * 16 + lq * 4] = pk;
      }
      const s8v pb0 = *(const s8v*)&Ps[w][lr][lq * 8];
      const s8v pb1 = *(const s8v*)&Ps[w][lr][32 + lq * 8];
#pragma unroll
      for (int dt = 0; dt < 4; dt++) {
        s8v a0 = *(const s8v*)&kvsT[dt * 16 + lr][lq * 8];
        s8v a1 = *(const s8v*)&kvsT[dt * 16 + lr][32 + lq * 8];
        oaccT[hh][dt] = __builtin_amdgcn_mfma_f32_16x16x32_bf16(a0, pb0, oaccT[hh][dt], 0, 0, 0);
        oaccT[hh][dt] = __builtin_amdgcn_mfma_f32_16x16x32_bf16(a1, pb1, oaccT[hh][dt], 0, 0, 0);
      }
    }
  }

  // final l reduction (once) + epilogue per head via wave-local Ps transpose
#pragma unroll
  for (int hh = 0; hh < 2; hh++) {
    float lt = l_lane[hh];
    lt += __shfl_xor(lt, 16);
    lt += __shfl_xor(lt, 32);
    const float inv = 1.0f / lt;
#pragma unroll
    for (int dt = 0; dt < 4; dt++) {
      s4v pk;
#pragma unroll
      for (int r = 0; r < 4; r++) {
        bf16 h16 = __float2bfloat16(oaccT[hh][dt][r] * inv);
        pk[r] = *(short*)&h16;
      }
      *(s4v*)&Ps[w][lr][dt * 16 + lq * 4] = pk;  // Ps[w][i][d] = O
    }
    const int orow = l >> 2, od = (l & 3) * 16;
    s8v o0 = *(const s8v*)&Ps[w][orow][od];
    s8v o1 = *(const s8v*)&Ps[w][orow][od + 8];
    bf16* op = o + ((size_t)(b * SEQ) + q0 + w * 16 + orow) * DIM + hp * 128 + hh * 64 + od;
    *(s8v*)&op[0] = o0;
    *(s8v*)&op[8] = o1;
  }
}

// ---------------------------------------------------------------------------
// Inputs fp32, output fp32 (32 MB d_out). d_out staging: q(bf16)@0..16MB,
// kvbufT@16MB (1.03MB) — dead before final fp32 GEMM. ws 35.1MB: att@0 16MB
// (WqT@0/WkvT@+2MB alias, dead pre-attn) | xb@16MB | WoutT@32MB | kvbuf@34MB.
// ---------------------------------------------------------------------------
extern "C" void kernel_launch(void* const* d_in, const int* in_sizes, int n_in,
                              void* d_out, int out_size, void* d_ws, size_t ws_size,
                              hipStream_t stream) {
  const float* x       = (const float*)d_in[0];
  const float* Wq      = (const float*)d_in[1];
  const float* Wkv     = (const float*)d_in[2];
  const float* null_kv = (const float*)d_in[3];
  const float* Wout    = (const float*)d_in[4];
  float* out = (float*)d_out;

  char* dob = (char*)d_out;
  bf16* q      = (bf16*)dob;                                // 16 MB
  bf16* kvbufT = (bf16*)(dob + (size_t)16 * 1024 * 1024);   // 1.03 MB
  char* p = (char*)d_ws;
  bf16* att   = (bf16*)p;
  bf16* xb    = (bf16*)(p + (size_t)16 * 1024 * 1024);
  bf16* WoutT = (bf16*)(p + (size_t)32 * 1024 * 1024);
  bf16* kvbuf = (bf16*)(p + (size_t)34 * 1024 * 1024);
  bf16* WqT   = att;
  bf16* WkvT  = att + (size_t)DIM * DIM;

  convert_kernel<<<(BATCH * SEQ * DIM) / (256 * 8), 256, 0, stream>>>(x, xb);

  const dim3 tb(32, 8);
  transpose_kernel<<<dim3(32, 32), tb, 0, stream>>>(Wq,   WqT,   DIM, DIM);
  transpose_kernel<<<dim3(2, 32),  tb, 0, stream>>>(Wkv,  WkvT,  DIM, DHEAD);
  transpose_kernel<<<dim3(32, 32), tb, 0, stream>>>(Wout, WoutT, DIM, DIM);

  // q = x @ Wq * (DHEAD^-0.5 * log2e) -> bf16 in d_out
  gemm_async_kernel<bf16><<<dim3(128, 8), 256, 0, stream>>>(xb, WqT, q, DIM, DIM,
                                                            0.125f * 1.44269504089f);
  gemm_kv_kernel<<<64, 256, 0, stream>>>(xb, WkvT, kvbuf, kvbufT, DIM);
  fill_null_tail_kernel<<<(BATCH * 64 * 64) / 256, 256, 0, stream>>>(null_kv, kvbuf, kvbufT);

  // attention: 2 heads/block, 1024 blocks
  attn_kernel<<<32 * 8 * BATCH, 256, 0, stream>>>(q, kvbuf, kvbufT, att);

  // out = att @ Wout -> d_out fp32 (q, kvbufT dead)
  gemm_async_kernel<float><<<dim3(128, 8), 256, 0, stream>>>(att, WoutT, out, DIM, DIM, 1.0f);
}

// Round 9
// 247.984 us; speedup vs baseline: 1.0476x; 1.0476x over previous
//
#include <hip/hip_runtime.h>
#include <hip/hip_bf16.h>

#define HEADS  16
#define DHEAD  64
#define BATCH  4
#define SEQ    2048
#define DIM    1024
#define KVROWS 2112   // 2049 (null + SEQ) padded up to multiple of 64
#define CSHIFT 24.0f  // static softmax shift (log2 domain); s' ~ N(0,1.44)

typedef __hip_bfloat16 bf16;
typedef __attribute__((ext_vector_type(8))) short s8v;   // 8 x bf16 (4 VGPRs)
typedef __attribute__((ext_vector_type(4))) short s4v;   // 4 x bf16
typedef __attribute__((ext_vector_type(4))) float f4v;   // MFMA accumulator

// async global->LDS, 16B per lane, dest = wave-uniform base + lane*16
__device__ __forceinline__ void gl_lds16(const void* g, void* l) {
  __builtin_amdgcn_global_load_lds(
      (const __attribute__((address_space(1))) unsigned int*)g,
      (__attribute__((address_space(3))) unsigned int*)l, 16, 0, 0);
}

// ---------------------------------------------------------------------------
// fp32 -> bf16 bulk convert (8 elements/thread)
// ---------------------------------------------------------------------------
__global__ void convert_kernel(const float* __restrict__ in, bf16* __restrict__ out) {
  const size_t i = ((size_t)blockIdx.x * 256 + threadIdx.x) * 8;
  const float4 a = *(const float4*)&in[i];
  const float4 b = *(const float4*)&in[i + 4];
  bf16 v[8] = {__float2bfloat16(a.x), __float2bfloat16(a.y),
               __float2bfloat16(a.z), __float2bfloat16(a.w),
               __float2bfloat16(b.x), __float2bfloat16(b.y),
               __float2bfloat16(b.z), __float2bfloat16(b.w)};
  *(s8v*)&out[i] = *(s8v*)v;
}

// ---------------------------------------------------------------------------
// Transpose+convert: fp32 [R][C] -> bf16 [C][R]; R,C multiples of 32
// ---------------------------------------------------------------------------
__global__ void transpose_kernel(const float* __restrict__ in, bf16* __restrict__ out,
                                 int R, int C) {
  __shared__ bf16 tile[32][33];
  const int c0 = blockIdx.x * 32, r0 = blockIdx.y * 32;
  const int tx = threadIdx.x, ty = threadIdx.y;
#pragma unroll
  for (int i = 0; i < 32; i += 8)
    tile[ty + i][tx] = __float2bfloat16(in[(size_t)(r0 + ty + i) * C + c0 + tx]);
  __syncthreads();
#pragma unroll
  for (int i = 0; i < 32; i += 8)
    out[(size_t)(c0 + ty + i) * R + r0 + tx] = tile[tx][ty + i];
}

// ---------------------------------------------------------------------------
// m97-style async GEMM (r7 config, known-good): 128x128 tile, BK=32, 4 waves
// (2x2, 64x64 each, 4x4 MFMA 16x16x32 frags). global_load_lds w16 staging
// into UNPADDED tiles; bank swizzle embedded in the per-lane GLOBAL address.
// ---------------------------------------------------------------------------
template <typename OT>
__global__ __launch_bounds__(256) void gemm_async_kernel(
    const bf16* __restrict__ A, const bf16* __restrict__ BT,
    OT* __restrict__ C, int K, int c_ld, float alpha) {
  __shared__ bf16 As[128 * 32];  // 8 KB
  __shared__ bf16 Bs[128 * 32];  // 8 KB
  const int m0 = blockIdx.x * 128, n0 = blockIdx.y * 128;
  const int t = threadIdx.x;
  const int w = t >> 6, l = t & 63, lr = l & 15, lq = l >> 4;
  const int wm = (w & 1) * 64, wn = (w >> 1) * 64;
  f4v acc[4][4] = {};

  const int rowl = l >> 2;
  const int cl = ((l & 3) ^ ((l >> 3) & 3)) * 8;
  const bf16* gA0 = A  + (size_t)(m0 + 32 * w + rowl) * K + cl;
  const bf16* gA1 = A  + (size_t)(m0 + 32 * w + 16 + rowl) * K + cl;
  const bf16* gB0 = BT + (size_t)(n0 + 32 * w + rowl) * K + cl;
  const bf16* gB1 = BT + (size_t)(n0 + 32 * w + 16 + rowl) * K + cl;
  bf16* lA0 = As + (2 * w) * 512;
  bf16* lA1 = As + (2 * w + 1) * 512;
  bf16* lB0 = Bs + (2 * w) * 512;
  bf16* lB1 = Bs + (2 * w + 1) * 512;

  const int sw = lq ^ ((lr >> 1) & 3);
  const s8v* As16 = (const s8v*)As;
  const s8v* Bs16 = (const s8v*)Bs;

  for (int k0 = 0; k0 < K; k0 += 32) {
    __syncthreads();
    gl_lds16(gA0 + k0, lA0);
    gl_lds16(gA1 + k0, lA1);
    gl_lds16(gB0 + k0, lB0);
    gl_lds16(gB1 + k0, lB1);
    __syncthreads();
    s8v a[4], b[4];
#pragma unroll
    for (int mt = 0; mt < 4; mt++) a[mt] = As16[(wm + mt * 16 + lr) * 4 + sw];
#pragma unroll
    for (int ct = 0; ct < 4; ct++) b[ct] = Bs16[(wn + ct * 16 + lr) * 4 + sw];
#pragma unroll
    for (int mt = 0; mt < 4; mt++)
#pragma unroll
      for (int ct = 0; ct < 4; ct++)
        acc[mt][ct] = __builtin_amdgcn_mfma_f32_16x16x32_bf16(a[mt], b[ct], acc[mt][ct], 0, 0, 0);
  }
#pragma unroll
  for (int mt = 0; mt < 4; mt++)
#pragma unroll
    for (int ct = 0; ct < 4; ct++)
#pragma unroll
      for (int r = 0; r < 4; r++) {
        const int row = m0 + wm + mt * 16 + lq * 4 + r;
        const int col = n0 + wn + ct * 16 + lr;
        const float v = acc[mt][ct][r] * alpha;
        if constexpr (__is_same(OT, float)) C[(size_t)row * c_ld + col] = v;
        else                                C[(size_t)row * c_ld + col] = __float2bfloat16(v);
      }
}

// ---------------------------------------------------------------------------
// KV GEMM: kv = x @ WkvT^T (N=64), dual-layout epilogue -> kvbuf + kvbufT.
// ---------------------------------------------------------------------------
__global__ __launch_bounds__(256) void gemm_kv_kernel(
    const bf16* __restrict__ A, const bf16* __restrict__ BT,
    bf16* __restrict__ kvbuf, bf16* __restrict__ kvbufT, int K) {
  __shared__ bf16 As[128][32];
  __shared__ bf16 Bs[64][32];
  const int m0 = blockIdx.x * 128;
  const int t = threadIdx.x;
  const int w = t >> 6, l = t & 63, lr = l & 15, lq = l >> 4;
  f4v acc[2][4] = {};
  const int arow = t >> 1, acol = (t & 1) * 16;
  const int brow = t >> 2, bcol = (t & 3) * 8;

  for (int k0 = 0; k0 < K; k0 += 32) {
    __syncthreads();
    *(s8v*)&As[arow][acol]     = *(const s8v*)&A[(size_t)(m0 + arow) * K + k0 + acol];
    *(s8v*)&As[arow][acol + 8] = *(const s8v*)&A[(size_t)(m0 + arow) * K + k0 + acol + 8];
    *(s8v*)&Bs[brow][bcol]     = *(const s8v*)&BT[(size_t)brow * K + k0 + bcol];
    __syncthreads();
    s8v a0 = *(const s8v*)&As[w * 32 + lr][lq * 8];
    s8v a1 = *(const s8v*)&As[w * 32 + 16 + lr][lq * 8];
#pragma unroll
    for (int ct = 0; ct < 4; ct++) {
      s8v bf = *(const s8v*)&Bs[ct * 16 + lr][lq * 8];
      acc[0][ct] = __builtin_amdgcn_mfma_f32_16x16x32_bf16(a0, bf, acc[0][ct], 0, 0, 0);
      acc[1][ct] = __builtin_amdgcn_mfma_f32_16x16x32_bf16(a1, bf, acc[1][ct], 0, 0, 0);
    }
  }
#pragma unroll
  for (int mt = 0; mt < 2; mt++)
#pragma unroll
    for (int ct = 0; ct < 4; ct++)
#pragma unroll
      for (int r = 0; r < 4; r++) {
        const int m = m0 + w * 32 + mt * 16 + lq * 4 + r;
        const int col = ct * 16 + lr;
        const int bb = m >> 11, jj = (m & 2047) + 1;
        const bf16 v = __float2bfloat16(acc[mt][ct][r]);
        kvbuf [(size_t)(bb * KVROWS + jj) * DHEAD + col] = v;
        kvbufT[(size_t)(bb * DHEAD + col) * KVROWS + jj] = v;
      }
}

// ---------------------------------------------------------------------------
// Fill row 0 (null_kv) and tail rows 2049..2111 (zeros) in BOTH kv layouts.
// ---------------------------------------------------------------------------
__global__ void fill_null_tail_kernel(const float* __restrict__ null_kv,
                                      bf16* __restrict__ kvbuf,
                                      bf16* __restrict__ kvbufT) {
  const int idx = blockIdx.x * 256 + threadIdx.x;
  const int d = idx & 63;
  const int s = (idx >> 6) & 63;
  const int b = idx >> 12;
  const int row = (s == 0) ? 0 : 2048 + s;
  const bf16 v = (s == 0) ? __float2bfloat16(null_kv[d]) : __float2bfloat16(0.f);
  kvbuf [(size_t)(b * KVROWS + row) * DHEAD + d] = v;
  kvbufT[(size_t)(b * DHEAD + d) * KVROWS + row] = v;
}

// ---------------------------------------------------------------------------
// Transposed flash attention, 2 heads/block, static-shift softmax, and
// REGISTER-PREFETCH PIPELINE: next KV tile's global loads are issued during
// the current tile's compute; loop body = barrier -> ds_write(regs) ->
// barrier -> compute. Removes global-load latency from the per-tile serial
// chain (attn was latency-bound: occ 18%, VALU 60%, conflicts 0 in r8).
// ---------------------------------------------------------------------------
__global__ __launch_bounds__(256) void attn_kernel(
    const bf16* __restrict__ q,    // [B*SEQ][DIM] (pre-scaled by 0.125*log2e)
    const bf16* __restrict__ kv,   // [B][KVROWS][64]
    const bf16* __restrict__ kvT,  // [B][64][KVROWS]
    bf16* __restrict__ o) {        // [B*SEQ][DIM]
  __shared__ bf16 kvs [64][68];    // 8.5 KB
  __shared__ bf16 kvsT[64][68];    // 8.5 KB
  __shared__ bf16 Ps[4][16][68];   // 8.5 KB (wave-local, reused per head)
  const int t = threadIdx.x, w = t >> 6, l = t & 63, lr = l & 15, lq = l >> 4;
  const int blk = blockIdx.x;                 // 1024 = 32 qt x 8 hp x 4 b
  const int qt = 31 - (blk >> 5);             // longest q-tiles first
  const int rem = blk & 31, hp = rem >> 2, b = rem & 3;
  const int q0 = qt * 64;
  const int iw = q0 + w * 16 + lr;

  const bf16* qbase = q + ((size_t)(b * SEQ) + iw) * DIM + hp * 128;
  s8v qb[2][2];
#pragma unroll
  for (int hh = 0; hh < 2; hh++) {
    qb[hh][0] = *(const s8v*)&qbase[hh * 64 + lq * 8];
    qb[hh][1] = *(const s8v*)&qbase[hh * 64 + 32 + lq * 8];
  }

  f4v oaccT[2][4] = {};
  float l_lane[2] = {0.f, 0.f};
  const bf16* kvb  = kv  + (size_t)b * KVROWS * DHEAD;
  const bf16* kvTb = kvT + (size_t)b * DHEAD * KVROWS;
  const int jend = q0 + 65;
  const int srow = t >> 2, scol = (t & 3) * 16;

  // prefetch tile 0 into registers
  s8v rkv0 = *(const s8v*)&kvb[(size_t)srow * DHEAD + scol];
  s8v rkv1 = *(const s8v*)&kvb[(size_t)srow * DHEAD + scol + 8];
  s8v rkT0 = *(const s8v*)&kvTb[(size_t)srow * KVROWS + scol];
  s8v rkT1 = *(const s8v*)&kvTb[(size_t)srow * KVROWS + scol + 8];

  for (int j0 = 0; j0 < jend; j0 += 64) {
    __syncthreads();   // previous tile's readers done
    *(s8v*)&kvs[srow][scol]      = rkv0;
    *(s8v*)&kvs[srow][scol + 8]  = rkv1;
    *(s8v*)&kvsT[srow][scol]     = rkT0;
    *(s8v*)&kvsT[srow][scol + 8] = rkT1;
    __syncthreads();   // writes visible

    // issue next tile's loads (clamped; overlap with compute below)
    const int jn = min(j0 + 64, KVROWS - 64);
    rkv0 = *(const s8v*)&kvb[(size_t)(jn + srow) * DHEAD + scol];
    rkv1 = *(const s8v*)&kvb[(size_t)(jn + srow) * DHEAD + scol + 8];
    rkT0 = *(const s8v*)&kvTb[(size_t)srow * KVROWS + jn + scol];
    rkT1 = *(const s8v*)&kvTb[(size_t)srow * KVROWS + jn + scol + 8];

    // S^T for both heads (KV A-frags read once)
    f4v st[2][4];
#pragma unroll
    for (int jt = 0; jt < 4; jt++) {
      s8v a0 = *(const s8v*)&kvs[jt * 16 + lr][lq * 8];
      s8v a1 = *(const s8v*)&kvs[jt * 16 + lr][32 + lq * 8];
#pragma unroll
      for (int hh = 0; hh < 2; hh++) {
        f4v z = {-CSHIFT, -CSHIFT, -CSHIFT, -CSHIFT};
        z = __builtin_amdgcn_mfma_f32_16x16x32_bf16(a0, qb[hh][0], z, 0, 0, 0);
        z = __builtin_amdgcn_mfma_f32_16x16x32_bf16(a1, qb[hh][1], z, 0, 0, 0);
        st[hh][jt] = z;
      }
    }

    const bool diag = (j0 + 62 > q0 + w * 16);  // wave-uniform
#pragma unroll
    for (int hh = 0; hh < 2; hh++) {
      if (diag) {
#pragma unroll
        for (int jt = 0; jt < 4; jt++)
#pragma unroll
          for (int r = 0; r < 4; r++) {
            const int jg = j0 + jt * 16 + lq * 4 + r;
            if (jg > iw + 1) st[hh][jt][r] = -1e30f;
          }
      }
      float rs = 0.f;
#pragma unroll
      for (int jt = 0; jt < 4; jt++)
#pragma unroll
        for (int r = 0; r < 4; r++) {
          const float pv = exp2f(st[hh][jt][r]);
          st[hh][jt][r] = pv;
          rs += pv;
        }
      l_lane[hh] += rs;

      // P^T -> Ps[w] (wave-local), b64 writes
#pragma unroll
      for (int jt = 0; jt < 4; jt++) {
        s4v pk;
#pragma unroll
        for (int r = 0; r < 4; r++) {
          bf16 h16 = __float2bfloat16(st[hh][jt][r]);
          pk[r] = *(short*)&h16;
        }
        *(s4v*)&Ps[w][lr][jt * 16 + lq * 4] = pk;
      }
      const s8v pb0 = *(const s8v*)&Ps[w][lr][lq * 8];
      const s8v pb1 = *(const s8v*)&Ps[w][lr][32 + lq * 8];
#pragma unroll
      for (int dt = 0; dt < 4; dt++) {
        s8v a0 = *(const s8v*)&kvsT[dt * 16 + lr][lq * 8];
        s8v a1 = *(const s8v*)&kvsT[dt * 16 + lr][32 + lq * 8];
        oaccT[hh][dt] = __builtin_amdgcn_mfma_f32_16x16x32_bf16(a0, pb0, oaccT[hh][dt], 0, 0, 0);
        oaccT[hh][dt] = __builtin_amdgcn_mfma_f32_16x16x32_bf16(a1, pb1, oaccT[hh][dt], 0, 0, 0);
      }
    }
  }

  // final l reduction + epilogue per head via wave-local Ps transpose
#pragma unroll
  for (int hh = 0; hh < 2; hh++) {
    float lt = l_lane[hh];
    lt += __shfl_xor(lt, 16);
    lt += __shfl_xor(lt, 32);
    const float inv = 1.0f / lt;
#pragma unroll
    for (int dt = 0; dt < 4; dt++) {
      s4v pk;
#pragma unroll
      for (int r = 0; r < 4; r++) {
        bf16 h16 = __float2bfloat16(oaccT[hh][dt][r] * inv);
        pk[r] = *(short*)&h16;
      }
      *(s4v*)&Ps[w][lr][dt * 16 + lq * 4] = pk;  // Ps[w][i][d] = O
    }
    const int orow = l >> 2, od = (l & 3) * 16;
    s8v o0 = *(const s8v*)&Ps[w][orow][od];
    s8v o1 = *(const s8v*)&Ps[w][orow][od + 8];
    bf16* op = o + ((size_t)(b * SEQ) + q0 + w * 16 + orow) * DIM + hp * 128 + hh * 64 + od;
    *(s8v*)&op[0] = o0;
    *(s8v*)&op[8] = o1;
  }
}

// ---------------------------------------------------------------------------
// Inputs fp32, output fp32 (32 MB d_out). d_out staging: q(bf16)@0..16MB,
// kvbufT@16MB (1.03MB) — dead before final fp32 GEMM. ws 35.1MB: att@0 16MB
// (WqT@0/WkvT@+2MB alias, dead pre-attn) | xb@16MB | WoutT@32MB | kvbuf@34MB.
// ---------------------------------------------------------------------------
extern "C" void kernel_launch(void* const* d_in, const int* in_sizes, int n_in,
                              void* d_out, int out_size, void* d_ws, size_t ws_size,
                              hipStream_t stream) {
  const float* x       = (const float*)d_in[0];
  const float* Wq      = (const float*)d_in[1];
  const float* Wkv     = (const float*)d_in[2];
  const float* null_kv = (const float*)d_in[3];
  const float* Wout    = (const float*)d_in[4];
  float* out = (float*)d_out;

  char* dob = (char*)d_out;
  bf16* q      = (bf16*)dob;                                // 16 MB
  bf16* kvbufT = (bf16*)(dob + (size_t)16 * 1024 * 1024);   // 1.03 MB
  char* p = (char*)d_ws;
  bf16* att   = (bf16*)p;
  bf16* xb    = (bf16*)(p + (size_t)16 * 1024 * 1024);
  bf16* WoutT = (bf16*)(p + (size_t)32 * 1024 * 1024);
  bf16* kvbuf = (bf16*)(p + (size_t)34 * 1024 * 1024);
  bf16* WqT   = att;
  bf16* WkvT  = att + (size_t)DIM * DIM;

  convert_kernel<<<(BATCH * SEQ * DIM) / (256 * 8), 256, 0, stream>>>(x, xb);

  const dim3 tb(32, 8);
  transpose_kernel<<<dim3(32, 32), tb, 0, stream>>>(Wq,   WqT,   DIM, DIM);
  transpose_kernel<<<dim3(2, 32),  tb, 0, stream>>>(Wkv,  WkvT,  DIM, DHEAD);
  transpose_kernel<<<dim3(32, 32), tb, 0, stream>>>(Wout, WoutT, DIM, DIM);

  // q = x @ Wq * (DHEAD^-0.5 * log2e) -> bf16 in d_out
  gemm_async_kernel<bf16><<<dim3(64, 8), 256, 0, stream>>>(xb, WqT, q, DIM, DIM,
                                                           0.125f * 1.44269504089f);
  gemm_kv_kernel<<<64, 256, 0, stream>>>(xb, WkvT, kvbuf, kvbufT, DIM);
  fill_null_tail_kernel<<<(BATCH * 64 * 64) / 256, 256, 0, stream>>>(null_kv, kvbuf, kvbufT);

  // attention: 2 heads/block, 1024 blocks, register-prefetch pipeline
  attn_kernel<<<32 * 8 * BATCH, 256, 0, stream>>>(q, kvbuf, kvbufT, att);

  // out = att @ Wout -> d_out fp32 (q, kvbufT dead)
  gemm_async_kernel<float><<<dim3(64, 8), 256, 0, stream>>>(att, WoutT, out, DIM, DIM, 1.0f);
}